// Round 3
// baseline (282.745 us; speedup 1.0000x reference)
//
#include <hip/hip_runtime.h>
#include <hip/hip_cooperative_groups.h>

namespace cg = cooperative_groups;

// Problem constants (fixed by the reference file)
#define NN   1024      // nodes
#define FD   128       // input features
#define DD1  64        // hidden dim after W1
#define DD2  16        // edge-MLP dim
#define MAXM 16384     // max directed edges (2 * E_HALF)
#define ALPHA_C 0.1f

// Persistent device scratch (rebuilt from inputs every launch; deterministic)
__device__ __attribute__((aligned(16))) int g_T[NN * NN]; // (u,v) -> edge id + 1, 0 if none
__device__ int   g_deg[NN];
__device__ int   g_off[NN + 1];
__device__ int   g_adj_e[MAXM];      // CSR: directed edge id (u -> v)
__device__ int   g_adj_v[MAXM];      // CSR: neighbor v (sorted)
__device__ float g_dinv[NN];         // 1/sqrt(deg+1)
__device__ float g_x0[NN * DD1];     // feat@W1+b1
__device__ float g_x1[NN * DD1];
__device__ float g_x2[NN * DD1];     // final propagated features
__device__ float g_xe[MAXM * DD2];   // per-directed-edge MLP outputs
__device__ float g_mul[MAXM * DD2];

__device__ __forceinline__ void prop_phase(int tid, const float* __restrict__ xin,
                                           float* __restrict__ xout) {
    int u = tid >> 6;
    int d = tid & 63;
    int beg = g_off[u], end = g_off[u + 1];
    float acc = 0.f;
    for (int j = beg; j < end; ++j) {
        int v = g_adj_v[j];
        acc += g_dinv[v] * xin[v * DD1 + d];
    }
    float du = g_dinv[u];
    float ah = du * (acc + du * xin[u * DD1 + d]);   // includes self-loop
    xout[u * DD1 + d] = (1.0f - ALPHA_C) * ah + ALPHA_C * g_x0[u * DD1 + d];
}

// One cooperative kernel: 256 blocks x 256 threads (65536 threads, 1 block/CU).
__global__ void fused_k(const float* __restrict__ feat,
                        const float* __restrict__ W1,  const float* __restrict__ b1,
                        const float* __restrict__ Wm1, const float* __restrict__ bm1,
                        const float* __restrict__ Wm2, const float* __restrict__ bm2,
                        const float* __restrict__ W3,  const float* __restrict__ b3,
                        const int* __restrict__ ei0,   const int* __restrict__ ei1,
                        const int* __restrict__ pos,   float* __restrict__ out,
                        int M, int P) {
    cg::grid_group grid = cg::this_grid();
    const int tid = blockIdx.x * blockDim.x + threadIdx.x;   // 0..65535
    const int nthr = gridDim.x * blockDim.x;

    // ---- Phase A: zero g_T/g_deg + x0 = feat@W1 + b1 -------------------
    for (int i = tid; i < (NN * NN) / 4; i += nthr)
        ((int4*)g_T)[i] = make_int4(0, 0, 0, 0);
    if (tid < NN) g_deg[tid] = 0;
    {
        int n = tid >> 6, d = tid & 63;
        const float* fr = feat + n * FD;
        float acc = b1[d];
        #pragma unroll 8
        for (int k = 0; k < FD; ++k) acc += fr[k] * W1[k * DD1 + d];
        g_x0[tid] = acc;                                     // tid == n*64+d
    }
    grid.sync();

    // ---- Phase B: edge table + degrees ---------------------------------
    for (int e = tid; e < M; e += nthr) {
        int a = ei0[e], b = ei1[e];
        g_T[a * NN + b] = e + 1;          // unique (a,b) per e -> race-free
        atomicAdd(&g_deg[a], 1);
    }
    grid.sync();

    // ---- Phase C: single-wave exclusive scan of deg (+ dinv) -----------
    if (blockIdx.x == 0 && threadIdx.x < 64) {
        int lane = threadIdx.x;
        int base = lane * 16;
        int pre[16];
        int s = 0;
        #pragma unroll
        for (int i = 0; i < 16; ++i) {
            int d = g_deg[base + i];
            g_dinv[base + i] = rsqrtf((float)(d + 1));
            pre[i] = s;
            s += d;
        }
        int inc = s;
        #pragma unroll
        for (int o = 1; o < 64; o <<= 1) {
            int t = __shfl_up(inc, o);
            if (lane >= o) inc += t;
        }
        int excl = inc - s;
        #pragma unroll
        for (int i = 0; i < 16; ++i) g_off[base + i] = excl + pre[i];
        if (lane == 63) g_off[NN] = excl + s;
    }
    grid.sync();

    // ---- Phase D: deterministic CSR via ballot-compaction (wave per u) -
    {
        int u = tid >> 6;                  // 1024 waves == 1024 rows
        int lane = tid & 63;
        int base = g_off[u];
        int cnt = 0;
        for (int c0 = 0; c0 < NN; c0 += 64) {
            int eid = g_T[u * NN + c0 + lane];
            unsigned long long m = __ballot(eid > 0);
            if (eid > 0) {
                int p = __popcll(m & ((1ULL << lane) - 1ULL));
                g_adj_e[base + cnt + p] = eid - 1;
                g_adj_v[base + cnt + p] = c0 + lane;
            }
            cnt += __popcll(m);
        }
    }
    grid.sync();

    // ---- Phase E/F: two propagation rounds -----------------------------
    prop_phase(tid, g_x0, g_x1);
    grid.sync();
    prop_phase(tid, g_x1, g_x2);
    grid.sync();

    // ---- Phase G: edge MLP (xe, mul per directed edge) -----------------
    for (int t = tid; t < M * 32; t += nthr) {
        int e = t >> 5;
        int j = t & 31;
        int m = j & 15;
        const float* W = (j < 16) ? Wm1 : Wm2;
        const float* B = (j < 16) ? bm1 : bm2;
        float*       O = (j < 16) ? g_xe : g_mul;
        int a = ei0[e], b = ei1[e];
        const float* xa = g_x2 + a * DD1;
        const float* xb = g_x2 + b * DD1;
        float acc = B[m];
        #pragma unroll 8
        for (int k = 0; k < DD1; ++k) acc += xa[k] * W[k * DD2 + m];
        #pragma unroll 8
        for (int k = 0; k < DD1; ++k) acc += xb[k] * W[(DD1 + k) * DD2 + m];
        O[e * DD2 + m] = acc;
    }
    grid.sync();

    // ---- Phase H: per-query-pair phase, 16 lanes per pair --------------
    {
        int lane = threadIdx.x & 63;
        int grp  = lane >> 4;              // 4 pair-groups per wave
        int m    = lane & 15;
        int wave = tid >> 6;
        int p = wave * 4 + grp;            // 65536 threads == P*16 tasks
        if (p < P) {
            int u = pos[2 * p], w = pos[2 * p + 1];

            // xx = x2[u] . x2[w]  (16-lane split + reduce)
            const float* xu = g_x2 + u * DD1;
            const float* xw = g_x2 + w * DD1;
            float xx = 0.f;
            #pragma unroll
            for (int d = m; d < DD1; d += 16) xx += xu[d] * xw[d];
            #pragma unroll
            for (int o = 8; o; o >>= 1) xx += __shfl_xor(xx, o);

            // common-neighbor products: lane m prefetches neighbor j0+m
            float p0 = 0.f, p1 = 0.f;
            bool found = false;
            int beg = g_off[u], end = g_off[u + 1];
            for (int j0 = beg; j0 < end; j0 += 16) {
                int j = j0 + m;
                int t_vw = 0, e_uv = 0, e_wv = 0, e_vu = 0;
                if (j < end) {
                    int v  = g_adj_v[j];
                    e_uv   = g_adj_e[j];
                    t_vw   = g_T[v * NN + w];
                    e_vu   = g_T[v * NN + u] - 1;
                    e_wv   = g_T[w * NN + v] - 1;   // valid iff t_vw > 0
                }
                unsigned long long mask = __ballot(t_vw > 0);
                unsigned long long gm = (mask >> (grp * 16)) & 0xFFFFULL;
                if (gm) found = true;
                while (gm) {
                    int k = __ffsll(gm) - 1;
                    gm &= gm - 1;
                    int src = grp * 16 + k;
                    int a0 = __shfl(e_uv, src);
                    int b0 = __shfl(t_vw, src) - 1;
                    int a1 = __shfl(e_wv, src);
                    int b1 = __shfl(e_vu, src);
                    p0 += g_xe[a0 * DD2 + m] * g_mul[b0 * DD2 + m];
                    p1 += g_xe[a1 * DD2 + m] * g_mul[b1 * DD2 + m];
                }
            }

            int s_uw = g_T[u * NN + w];
            float res = xx;
            if (found || s_uw > 0) {
                float se = (s_uw > 0) ? 1.0f : 0.0f;
                float base = b3[m] + se * W3[16 * DD2 + m];
                float y0 = base, y1 = base;
                #pragma unroll
                for (int k = 0; k < DD2; ++k) {
                    float wk  = W3[k * DD2 + m];
                    float p0k = __shfl(p0, grp * 16 + k);
                    float p1k = __shfl(p1, grp * 16 + k);
                    y0 += p0k * wk;
                    y1 += p1k * wk;
                }
                float ef = y0 * y1;
                #pragma unroll
                for (int o = 8; o; o >>= 1) ef += __shfl_xor(ef, o);
                res += ef;
            }
            if (m == 0) out[p] = res;
        }
    }
}

// ----------------------------------------------------------------
extern "C" void kernel_launch(void* const* d_in, const int* in_sizes, int n_in,
                              void* d_out, int out_size, void* d_ws, size_t ws_size,
                              hipStream_t stream) {
    const float* feat = (const float*)d_in[0];
    const float* W1   = (const float*)d_in[1];
    const float* b1   = (const float*)d_in[2];
    const float* Wm1  = (const float*)d_in[3];
    const float* bm1  = (const float*)d_in[4];
    const float* Wm2  = (const float*)d_in[5];
    const float* bm2  = (const float*)d_in[6];
    const float* W3   = (const float*)d_in[7];
    const float* b3   = (const float*)d_in[8];
    const int*   ei   = (const int*)d_in[9];
    const int*   pos  = (const int*)d_in[10];
    float* out = (float*)d_out;

    int M = in_sizes[9] / 2;       // directed edges
    int P = in_sizes[10] / 2;      // query pairs
    const int* ei0 = ei;
    const int* ei1 = ei + M;

    void* args[] = { (void*)&feat, (void*)&W1, (void*)&b1,
                     (void*)&Wm1, (void*)&bm1, (void*)&Wm2, (void*)&bm2,
                     (void*)&W3, (void*)&b3,
                     (void*)&ei0, (void*)&ei1, (void*)&pos,
                     (void*)&out, (void*)&M, (void*)&P };
    hipLaunchCooperativeKernel((const void*)fused_k, dim3(256), dim3(256),
                               args, 0, stream);
}